// Round 11
// baseline (807.413 us; speedup 1.0000x reference)
//
#include <hip/hip_runtime.h>
#include <hip/hip_bf16.h>
#include <stdint.h>

#define KP   10112   // padded K for W1t: 158*64 (zero-padded past 10000)
#define DIN  10000
#define NB   8192
#define HID  1024
#define EMB  128
#define NI   79      // iterations: 79 * 2 k-tiles of 64 = 158

typedef __attribute__((ext_vector_type(8))) __bf16 bf16x8;
typedef __attribute__((ext_vector_type(4))) float  f32x4;

typedef const __attribute__((address_space(1))) void* gas_cp;
typedef __attribute__((address_space(3))) void* las_p;

__device__ __forceinline__ unsigned short f2bf(float f) {
    union { float f; unsigned u; } c; c.f = f;
    unsigned u = c.u;
    u += 0x7FFFu + ((u >> 16) & 1u);   // RNE
    return (unsigned short)(u >> 16);
}

// ---- fp32 src[K][N] -> bf16 dst[N][Kp] via LDS tile transpose ----
__global__ void conv_transpose(const float* __restrict__ src, unsigned short* __restrict__ dst,
                               int K, int N, int Kp) {
    __shared__ float tile[64][33];
    const int tx = threadIdx.x & 31, ty = threadIdx.x >> 5;
    const int k0 = blockIdx.x * 64, n0 = blockIdx.y * 32;
#pragma unroll
    for (int j = 0; j < 8; ++j) {
        int k = k0 + ty + j * 8;
        tile[ty + j * 8][tx] = (k < K) ? src[(size_t)k * N + n0 + tx] : 0.0f;
    }
    __syncthreads();
#pragma unroll
    for (int j = 0; j < 4; ++j) {
        int n = n0 + ty + j * 8;
        unsigned short lo = f2bf(tile[2 * tx][ty + j * 8]);
        unsigned short hi = f2bf(tile[2 * tx + 1][ty + j * 8]);
        unsigned int packed = (unsigned int)lo | ((unsigned int)hi << 16);
        *(unsigned int*)(dst + (size_t)n * Kp + k0 + 2 * tx) = packed;
    }
}

// order-pinned LDS fragment read (volatile asm => issue order == source order)
#define DSR(d, ad, off) asm volatile("ds_read_b128 %0, %1 offset:" off : "=v"(d) : "v"(ad))
// counted lgkm gate + scheduling fence (rule #18)
#define GATE(n) do { asm volatile("s_waitcnt lgkmcnt(" #n ")" ::: "memory"); \
                     __builtin_amdgcn_sched_barrier(0); } while (0)
#define SB0() __builtin_amdgcn_sched_barrier(0)

struct ARegs { float4 r0, r1, r2, r3; int ok; };

// ======== GEMM1 fused-A: 256x256, BK=64, 4-phase, A read DIRECTLY as fp32 ========
// conv_pad eliminated. A staging: 4 R-sets, load at alpha/beta/gamma/delta (one
// 128x64 fp32 half-tile each), cvt+swizzled ds_write 2-3 phases later (beta
// writes even-tile halves, delta writes odd-tile halves). wrA auto-waits are
// counted vmcnt(8-12) on >=2-phase-old data. Explicit gates: vmcnt(4) at
// beta/delta end (B-tile landed; newest 4 A-loads stay in flight) - R10 ledger.
// ds_writes issued BEFORE the phase's ds_reads (in-order DS retire keeps R10's
// GATE ladder numbers). B staging: global_load_lds, pre-swizzled source.
// LDS 160KB: A 3x32KB ring, B 2x32KB. Grid (8,32), bx=(side<<2)|bn.
__global__ __launch_bounds__(512, 2)
void gemm1_4pf(const float* __restrict__ Au, const float* __restrict__ Ai,
               const unsigned short* __restrict__ W1t,
               const float* __restrict__ b1u, const float* __restrict__ b1i,
               unsigned short* __restrict__ H1) {
    __shared__ __align__(16) unsigned short lds_[81920];   // A 3x16384, B 2x16384 @49152

    const int t  = threadIdx.x;
    const int lane = t & 63, wv = t >> 6;
    const int wm = wv >> 2, wn = wv & 3;
    const int rA = lane & 15, kg = lane >> 4;

    const int side = blockIdx.x >> 2, bn = blockIdx.x & 3, bm = blockIdx.y;

    const float* Asrc = side ? Ai : Au;
    const unsigned short* W1tS = W1t + (size_t)side * HID * KP;
    const float* bias = side ? b1i : b1u;
    unsigned short* Cout = H1 + (size_t)side * NB * HID;

    // A reg-staging: thread t -> row t>>2 (0..127 within half), 16 fp32 at (t&3)*16
    const int ar  = t >> 2;
    const int ag0 = (t & 3) * 2;                    // global 8-elem chunk pair base
    const float* gA = Asrc + (size_t)(bm * 256 + ar) * DIN + (t & 3) * 16;
    const int aw0 = ar * 64 + ((ag0       ^ (ar & 7)) * 8);   // swizzled LDS elem offs
    const int aw1 = ar * 64 + (((ag0 + 1) ^ (ar & 7)) * 8);

    // B staging: rows bn*256 + (t>>3) (+64), source k-chunk pre-swizzled
    const int rowSB = bn * 256 + (t >> 3);
    const int kcl   = ((t & 7) ^ ((t >> 3) & 7)) * 8;

    // frag-read swizzled k offsets (elements)
    const int xk0 = ((0 * 4 + kg) ^ (rA & 7)) * 8;
    const int xk1 = ((1 * 4 + kg) ^ (rA & 7)) * 8;

    const unsigned ldsB = (unsigned)(size_t)lds_;
    const unsigned aC0 = ldsB + wm * 16384 + rA * 128 + xk0 * 2;
    const unsigned aC1 = ldsB + wm * 16384 + rA * 128 + xk1 * 2;
    const unsigned bC0 = ldsB + 98304 + (wn >> 1) * 16384 + (wn & 1) * 8192 + rA * 128 + xk0 * 2;
    const unsigned bC1 = ldsB + 98304 + (wn >> 1) * 16384 + (wn & 1) * 8192 + rA * 128 + xk1 * 2;

    f32x4 acc[8][4] = {};
    bf16x8 a[4][2], b[4][2];
    ARegs G0, G1, G2, G3;

    auto ldA = [&](int tl, int h, ARegs& G) {
        G.ok = (tl * 64 + (t & 3) * 16) < DIN;      // 16-chunk is all-valid or all-OOB
        const float* p = gA + (size_t)(h * 128) * DIN + (G.ok ? tl * 64 : 0);
        G.r0 = *(const float4*)(p);
        G.r1 = *(const float4*)(p + 4);
        G.r2 = *(const float4*)(p + 8);
        G.r3 = *(const float4*)(p + 12);
    };
    auto wrA = [&](int buf, int h, ARegs& G) {
        const float4 z = make_float4(0.f, 0.f, 0.f, 0.f);
        const float4 r0 = G.ok ? G.r0 : z, r1 = G.ok ? G.r1 : z;
        const float4 r2 = G.ok ? G.r2 : z, r3 = G.ok ? G.r3 : z;
        bf16x8 v0, v1;
        v0[0] = (__bf16)r0.x; v0[1] = (__bf16)r0.y; v0[2] = (__bf16)r0.z; v0[3] = (__bf16)r0.w;
        v0[4] = (__bf16)r1.x; v0[5] = (__bf16)r1.y; v0[6] = (__bf16)r1.z; v0[7] = (__bf16)r1.w;
        v1[0] = (__bf16)r2.x; v1[1] = (__bf16)r2.y; v1[2] = (__bf16)r2.z; v1[3] = (__bf16)r2.w;
        v1[4] = (__bf16)r3.x; v1[5] = (__bf16)r3.y; v1[6] = (__bf16)r3.z; v1[7] = (__bf16)r3.w;
        unsigned short* d = lds_ + buf * 16384 + h * 8192;
        *(bf16x8*)(d + aw0) = v0;
        *(bf16x8*)(d + aw1) = v1;
    };
    auto stB = [&](int tile, int h, int par) {
        const unsigned short* s = W1tS + (size_t)(rowSB + h * 128) * KP + tile * 64 + kcl;
        __builtin_amdgcn_global_load_lds((gas_cp)s, (las_p)(lds_ + 49152 + par * 16384 + h * 8192 + wv * 512), 16, 0, 0);
        __builtin_amdgcn_global_load_lds((gas_cp)(s + (size_t)64 * KP), (las_p)(lds_ + 49152 + par * 16384 + h * 8192 + 4096 + wv * 512), 16, 0, 0);
    };

    auto rdB01 = [&](int par) {
        unsigned b0 = bC0 + par * 32768, b1 = bC1 + par * 32768;
        DSR(b[0][0], b0, "0");    DSR(b[0][1], b1, "0");
        DSR(b[1][0], b0, "2048"); DSR(b[1][1], b1, "2048");
    };
    auto rdB23 = [&](int par) {
        unsigned b0 = bC0 + par * 32768 + 4096, b1 = bC1 + par * 32768 + 4096;
        DSR(b[2][0], b0, "0");    DSR(b[2][1], b1, "0");
        DSR(b[3][0], b0, "2048"); DSR(b[3][1], b1, "2048");
    };
    auto rdA4 = [&](int buf, int mq) {
        unsigned a0 = aC0 + buf * 32768 + mq * 8192, a1 = aC1 + buf * 32768 + mq * 8192;
        DSR(a[0][0], a0, "0");    DSR(a[0][1], a1, "0");
        DSR(a[1][0], a0, "2048"); DSR(a[1][1], a1, "2048");
        DSR(a[2][0], a0, "4096"); DSR(a[2][1], a1, "4096");
        DSR(a[3][0], a0, "6144"); DSR(a[3][1], a1, "6144");
    };
    auto mmj = [&](int mq, int j, int nq) {
        acc[mq*4+j][nq*2+0] = __builtin_amdgcn_mfma_f32_16x16x32_bf16(a[j][0], b[nq*2+0][0], acc[mq*4+j][nq*2+0], 0, 0, 0);
        acc[mq*4+j][nq*2+0] = __builtin_amdgcn_mfma_f32_16x16x32_bf16(a[j][1], b[nq*2+0][1], acc[mq*4+j][nq*2+0], 0, 0, 0);
        acc[mq*4+j][nq*2+1] = __builtin_amdgcn_mfma_f32_16x16x32_bf16(a[j][0], b[nq*2+1][0], acc[mq*4+j][nq*2+1], 0, 0, 0);
        acc[mq*4+j][nq*2+1] = __builtin_amdgcn_mfma_f32_16x16x32_bf16(a[j][1], b[nq*2+1][1], acc[mq*4+j][nq*2+1], 0, 0, 0);
    };
    auto mmcol = [&](int mq, int col) {
#pragma unroll
        for (int j = 0; j < 4; ++j) {
            acc[mq*4+j][col] = __builtin_amdgcn_mfma_f32_16x16x32_bf16(a[j][0], b[col][0], acc[mq*4+j][col], 0, 0, 0);
            acc[mq*4+j][col] = __builtin_amdgcn_mfma_f32_16x16x32_bf16(a[j][1], b[col][1], acc[mq*4+j][col], 0, 0, 0);
        }
    };

    // ---- prologue: A(0)->buf0, A(1)->buf1 via regs; B(0)->par0; prime G0/G1=A(2) ----
    ldA(0, 0, G0); ldA(0, 1, G1);
    SB0();
    stB(0, 0, 0); stB(0, 1, 0);
    SB0();
    ldA(1, 0, G2); ldA(1, 1, G3);
    SB0();
    wrA(0, 0, G0); wrA(0, 1, G1);   // auto vmcnt waits (counted)
    wrA(1, 0, G2); wrA(1, 1, G3);   // last one drains stB(0) too
    SB0();
    ldA(2, 0, G0); ldA(2, 1, G1);
    asm volatile("s_waitcnt lgkmcnt(0)" ::: "memory");
    __builtin_amdgcn_s_barrier();

    int cA0 = 0, cA1 = 1, nA = 2;
    for (int i = 0; i < NI - 1; ++i) {
        const int T1 = 2 * i + 1, SB_ = 2 * i + 2, S1 = 2 * i + 3, S0n = 2 * i + 4;
        // ---- alpha: ldA(S1,h0)->G2; stage B(T1)->par1; mq0 of cA0 ----
        ldA(S1, 0, G2);
        SB0();
        stB(T1, 0, 1); stB(T1, 1, 1);
        SB0();
        rdB01(0); rdA4(cA0, 0); rdB23(0);
        __builtin_amdgcn_s_setprio(1);
        GATE(10); mmj(0,0,0); GATE(8); mmj(0,1,0); GATE(6); mmj(0,2,0);
        GATE(4);  mmj(0,3,0); GATE(2); mmcol(0,2); GATE(0); mmcol(0,3);
        __builtin_amdgcn_s_setprio(0);
        __builtin_amdgcn_s_barrier();
        // ---- beta: write A(SB_)->nA; ldA(S1,h1)->G3; mq1 of cA0; gate B(T1) ----
        wrA(nA, 0, G0); wrA(nA, 1, G1);     // auto vmcnt (2-3 phase gap)
        SB0();
        ldA(S1, 1, G3);
        SB0();
        rdA4(cA0, 1);
        __builtin_amdgcn_s_setprio(1);
        GATE(6); mmj(1,0,0); GATE(4); mmj(1,1,0); GATE(2); mmj(1,2,0);
        GATE(0); mmj(1,3,0); mmcol(1,2); mmcol(1,3);
        __builtin_amdgcn_s_setprio(0);
        asm volatile("s_waitcnt vmcnt(4)" ::: "memory");
        __builtin_amdgcn_s_barrier();
        // ---- gamma: ldA(S0n,h0)->G0; stage B(SB_)->par0; mq0 of cA1 ----
        ldA(S0n, 0, G0);
        SB0();
        stB(SB_, 0, 0); stB(SB_, 1, 0);
        SB0();
        rdB01(1); rdA4(cA1, 0); rdB23(1);
        __builtin_amdgcn_s_setprio(1);
        GATE(10); mmj(0,0,0); GATE(8); mmj(0,1,0); GATE(6); mmj(0,2,0);
        GATE(4);  mmj(0,3,0); GATE(2); mmcol(0,2); GATE(0); mmcol(0,3);
        __builtin_amdgcn_s_setprio(0);
        __builtin_amdgcn_s_barrier();
        // ---- delta: write A(S1)->cA0; ldA(S0n,h1)->G1; mq1 of cA1; gate B(SB_) ----
        wrA(cA0, 0, G2); wrA(cA0, 1, G3);
        SB0();
        ldA(S0n, 1, G1);
        SB0();
        rdA4(cA1, 1);
        __builtin_amdgcn_s_setprio(1);
        GATE(6); mmj(1,0,0); GATE(4); mmj(1,1,0); GATE(2); mmj(1,2,0);
        GATE(0); mmj(1,3,0); mmcol(1,2); mmcol(1,3);
        __builtin_amdgcn_s_setprio(0);
        asm volatile("s_waitcnt vmcnt(4)" ::: "memory");
        __builtin_amdgcn_s_barrier();
        // rotate A ring: (cA0,cA1,nA) <- (nA,cA0,cA1)
        int tmp = cA1; cA1 = cA0; cA0 = nA; nA = tmp;
    }
    // ---- final iteration: tiles 156 (cA0/par0), 157 (cA1/par1); A already staged ----
    {
        const int TL = 2 * NI - 1;
        // alpha_L
        stB(TL, 0, 1); stB(TL, 1, 1);
        SB0();
        rdB01(0); rdA4(cA0, 0); rdB23(0);
        __builtin_amdgcn_s_setprio(1);
        GATE(10); mmj(0,0,0); GATE(8); mmj(0,1,0); GATE(6); mmj(0,2,0);
        GATE(4);  mmj(0,3,0); GATE(2); mmcol(0,2); GATE(0); mmcol(0,3);
        __builtin_amdgcn_s_setprio(0);
        __builtin_amdgcn_s_barrier();
        // beta_L: drain everything (junk prefetch loads + B(TL))
        rdA4(cA0, 1);
        __builtin_amdgcn_s_setprio(1);
        GATE(6); mmj(1,0,0); GATE(4); mmj(1,1,0); GATE(2); mmj(1,2,0);
        GATE(0); mmj(1,3,0); mmcol(1,2); mmcol(1,3);
        __builtin_amdgcn_s_setprio(0);
        asm volatile("s_waitcnt vmcnt(0)" ::: "memory");
        __builtin_amdgcn_s_barrier();
        // gamma_L
        rdB01(1); rdA4(cA1, 0); rdB23(1);
        __builtin_amdgcn_s_setprio(1);
        GATE(10); mmj(0,0,0); GATE(8); mmj(0,1,0); GATE(6); mmj(0,2,0);
        GATE(4);  mmj(0,3,0); GATE(2); mmcol(0,2); GATE(0); mmcol(0,3);
        __builtin_amdgcn_s_setprio(0);
        __builtin_amdgcn_s_barrier();
        // delta_L
        rdA4(cA1, 1);
        __builtin_amdgcn_s_setprio(1);
        GATE(6); mmj(1,0,0); GATE(4); mmj(1,1,0); GATE(2); mmj(1,2,0);
        GATE(0); mmj(1,3,0); mmcol(1,2); mmcol(1,3);
        __builtin_amdgcn_s_setprio(0);
    }

    // epilogue: frag row = kg*4+reg, col = rA; bias+relu -> bf16
    const int rowbase = bm * 256 + wm * 128 + kg * 4;
    const int colbase = bn * 256 + wn * 64 + rA;
#pragma unroll
    for (int ni = 0; ni < 4; ++ni) {
        const int col = colbase + ni * 16;
        const float bv = bias[col];
#pragma unroll
        for (int mi = 0; mi < 8; ++mi) {
#pragma unroll
            for (int rr = 0; rr < 4; ++rr) {
                float v = fmaxf(acc[mi][ni][rr] + bv, 0.0f);
                Cout[(size_t)(rowbase + mi * 16 + rr) * HID + col] = f2bf(v);
            }
        }
    }
}

// ======== GEMM2 K-split: PQh[kh*2+side] = H1[side][:,kh*512:+512] @ W2t + b2(kh==0) ========
__global__ __launch_bounds__(256, 2)
void gemm2k(const unsigned short* __restrict__ H1,
            const unsigned short* __restrict__ W2t,
            const float* __restrict__ b2u, const float* __restrict__ b2i,
            float* __restrict__ PQh) {
    __shared__ unsigned short As[3 * 4096];
    __shared__ unsigned short Bs[3 * 4096];

    const int t = threadIdx.x, lane = t & 63, wave = t >> 6;
    const int wr = wave >> 1, wc = wave & 1, rA = lane & 15, kg = lane >> 4;
    const int kh = blockIdx.x, bm = blockIdx.y, side = blockIdx.z;
    const int nk = 512 / 32;

    const unsigned short* A  = H1  + (size_t)side * NB * HID + kh * 512;
    const unsigned short* Bt = W2t + (size_t)side * EMB * HID + kh * 512;
    const float* bias = side ? b2i : b2u;
    float* Cout = PQh + (size_t)(kh * 2 + side) * NB * EMB;

    const int srcc = (t & 3) ^ ((t >> 3) & 3);
    const unsigned short* ga = A  + (size_t)(bm * 128 + (t >> 2)) * HID + (size_t)srcc * 8;
    const unsigned short* gb = Bt + (size_t)(t >> 2) * HID + (size_t)srcc * 8;
    const size_t aP = (size_t)64 * HID;

    f32x4 acc[4][4] = {};
    const int swz  = (rA >> 1) & 3;
    const int aoff = (wr * 64 + rA) * 32 + (kg ^ swz) * 8;
    const int boff = (wc * 64 + rA) * 32 + (kg ^ swz) * 8;
    const int wst  = wave * 512;

    auto stage = [&](int buf) {
        const int bo = buf << 12;
        __builtin_amdgcn_global_load_lds((gas_cp)(ga),      (las_p)(As + bo + wst),        16, 0, 0);
        __builtin_amdgcn_global_load_lds((gas_cp)(ga + aP), (las_p)(As + bo + wst + 2048), 16, 0, 0);
        __builtin_amdgcn_global_load_lds((gas_cp)(gb),      (las_p)(Bs + bo + wst),        16, 0, 0);
        __builtin_amdgcn_global_load_lds((gas_cp)(gb + aP), (las_p)(Bs + bo + wst + 2048), 16, 0, 0);
        ga += 32; gb += 32;
    };
    auto compute = [&](int buf) {
        const int bo = buf << 12;
        bf16x8 af[4], bfr[4];
#pragma unroll
        for (int m = 0; m < 4; ++m) af[m]  = *(const bf16x8*)(As + bo + aoff + m * 512);
#pragma unroll
        for (int n = 0; n < 4; ++n) bfr[n] = *(const bf16x8*)(Bs + bo + boff + n * 512);
#pragma unroll
        for (int m = 0; m < 4; ++m)
#pragma unroll
            for (int n = 0; n < 4; ++n)
                acc[m][n] = __builtin_amdgcn_mfma_f32_16x16x32_bf16(af[m], bfr[n], acc[m][n], 0, 0, 0);
    };

    stage(0); stage(1);
    int cur = 0;
    for (int kt = 0; kt < nk - 2; ++kt) {
        int pfb = cur + 2; if (pfb >= 3) pfb -= 3;
        stage(pfb);
        asm volatile("s_waitcnt vmcnt(8)" ::: "memory");
        __builtin_amdgcn_s_barrier();
        compute(cur);
        __builtin_amdgcn_s_barrier();
        cur = (cur + 1 == 3) ? 0 : cur + 1;
    }
    asm volatile("s_waitcnt vmcnt(4)" ::: "memory");
    __builtin_amdgcn_s_barrier();
    compute(cur);
    cur = (cur + 1 == 3) ? 0 : cur + 1;
    asm volatile("s_waitcnt vmcnt(0)" ::: "memory");
    __builtin_amdgcn_s_barrier();
    compute(cur);

    const int rowbase = bm * 128 + wr * 64 + kg * 4;
    const int colbase = wc * 64 + rA;
#pragma unroll
    for (int n = 0; n < 4; ++n) {
        const int col = colbase + n * 16;
        const float bv = (kh == 0) ? bias[col] : 0.0f;
#pragma unroll
        for (int m = 0; m < 4; ++m) {
#pragma unroll
            for (int r = 0; r < 4; ++r) {
                Cout[(size_t)(rowbase + m * 16 + r) * EMB + col] = acc[m][n][r] + bv;
            }
        }
    }
}

// ---- out[i] = sum_e (P0+P1)[i][e] * (Q0+Q1)[i][e] ----
__global__ void rowdot4(const float* __restrict__ PQh, float* __restrict__ out, int n) {
    int gid = blockIdx.x * blockDim.x + threadIdx.x;
    int w = gid >> 6, lane = gid & 63;
    if (w >= n) return;
    const size_t C = (size_t)NB * EMB;
    const float2 p0 = ((const float2*)(PQh + 0 * C + (size_t)w * EMB))[lane];
    const float2 q0 = ((const float2*)(PQh + 1 * C + (size_t)w * EMB))[lane];
    const float2 p1 = ((const float2*)(PQh + 2 * C + (size_t)w * EMB))[lane];
    const float2 q1 = ((const float2*)(PQh + 3 * C + (size_t)w * EMB))[lane];
    const float px = p0.x + p1.x, py = p0.y + p1.y;
    const float qx = q0.x + q1.x, qy = q0.y + q1.y;
    float s = px * qx + py * qy;
#pragma unroll
    for (int off = 32; off; off >>= 1) s += __shfl_down(s, off);
    if (lane == 0) out[w] = s;
}

extern "C" void kernel_launch(void* const* d_in, const int* in_sizes, int n_in,
                              void* d_out, int out_size, void* d_ws, size_t ws_size,
                              hipStream_t stream) {
    const float* user = (const float*)d_in[0];
    const float* item = (const float*)d_in[1];
    const float* Wu1  = (const float*)d_in[2];
    const float* bu1  = (const float*)d_in[3];
    const float* Wu2  = (const float*)d_in[4];
    const float* bu2  = (const float*)d_in[5];
    const float* Wi1  = (const float*)d_in[6];
    const float* bi1  = (const float*)d_in[7];
    const float* Wi2  = (const float*)d_in[8];
    const float* bi2  = (const float*)d_in[9];
    float* out = (float*)d_out;

    char* ws = (char*)d_ws;
    size_t off = 0;
    auto alloc = [&](size_t bytes) {
        char* p = ws + off;
        off += (bytes + 255) & ~(size_t)255;
        return p;
    };

    unsigned short* W1t = (unsigned short*)alloc((size_t)2 * HID * KP * 2);  // [2][1024][10112]
    unsigned short* W2t = (unsigned short*)alloc((size_t)2 * EMB * HID * 2); // [2][128][1024]
    float* PQh = (float*)alloc((size_t)4 * NB * EMB * 4);                    // [kh*2+side][8192][128]
    unsigned short* H1 = (unsigned short*)alloc((size_t)2 * NB * HID * 2);   // [2][8192][1024]

    dim3 blk(256);
    conv_transpose<<<dim3(KP / 64, HID / 32), blk, 0, stream>>>(Wu1, W1t,                      DIN, HID, KP);
    conv_transpose<<<dim3(KP / 64, HID / 32), blk, 0, stream>>>(Wi1, W1t + (size_t)HID * KP,   DIN, HID, KP);
    conv_transpose<<<dim3(HID / 64, EMB / 32), blk, 0, stream>>>(Wu2, W2t,                     HID, EMB, HID);
    conv_transpose<<<dim3(HID / 64, EMB / 32), blk, 0, stream>>>(Wi2, W2t + (size_t)EMB * HID, HID, EMB, HID);

    gemm1_4pf<<<dim3(8, 32), dim3(512), 0, stream>>>(user, item, W1t, bu1, bi1, H1);
    gemm2k<<<dim3(2, 64, 2), blk, 0, stream>>>(H1, W2t, bu2, bi2, PQh);
    rowdot4<<<(NB * 64) / 256, blk, 0, stream>>>(PQh, out, NB);
}

// Round 12
// 482.496 us; speedup vs baseline: 1.6734x; 1.6734x over previous
//
#include <hip/hip_runtime.h>
#include <hip/hip_bf16.h>
#include <stdint.h>

#define KP   10112   // padded K: 158*64 (zero-padded past 10000)
#define DIN  10000
#define NB   8192
#define HID  1024
#define EMB  128
#define NI   79      // iterations: 79 * 2 k-tiles of 64 = 158

typedef __attribute__((ext_vector_type(8))) __bf16 bf16x8;
typedef __attribute__((ext_vector_type(4))) float  f32x4;
typedef __attribute__((ext_vector_type(4))) unsigned short ushort4v;

typedef const __attribute__((address_space(1))) void* gas_cp;
typedef __attribute__((address_space(3))) void* las_p;

__device__ __forceinline__ unsigned short f2bf(float f) {
    union { float f; unsigned u; } c; c.f = f;
    unsigned u = c.u;
    u += 0x7FFFu + ((u >> 16) & 1u);   // RNE
    return (unsigned short)(u >> 16);
}

// ---- fp32 [2][rows][DIN] -> bf16 [2][rows][KP] (side = blockIdx.z) ----
__global__ void conv_pad2(const float* __restrict__ user, const float* __restrict__ item,
                          unsigned short* __restrict__ dst) {
    const int c4  = blockIdx.x * blockDim.x + threadIdx.x;
    const int row = blockIdx.y;
    const int side = blockIdx.z;
    if (c4 >= KP / 4) return;
    const float* src = side ? item : user;
    unsigned short* d = dst + (size_t)side * NB * KP;
    ushort4v o;
    if (c4 < DIN / 4) {
        float4 a = *(const float4*)(src + (size_t)row * DIN + (size_t)c4 * 4);
        o[0] = f2bf(a.x); o[1] = f2bf(a.y); o[2] = f2bf(a.z); o[3] = f2bf(a.w);
    } else {
        o[0] = o[1] = o[2] = o[3] = 0;
    }
    *(ushort4v*)(d + (size_t)row * KP + (size_t)c4 * 4) = o;
}

// ---- fp32 src[K][N] -> bf16 dst[N][Kp] via LDS tile transpose ----
__global__ void conv_transpose(const float* __restrict__ src, unsigned short* __restrict__ dst,
                               int K, int N, int Kp) {
    __shared__ float tile[64][33];
    const int tx = threadIdx.x & 31, ty = threadIdx.x >> 5;
    const int k0 = blockIdx.x * 64, n0 = blockIdx.y * 32;
#pragma unroll
    for (int j = 0; j < 8; ++j) {
        int k = k0 + ty + j * 8;
        tile[ty + j * 8][tx] = (k < K) ? src[(size_t)k * N + n0 + tx] : 0.0f;
    }
    __syncthreads();
#pragma unroll
    for (int j = 0; j < 4; ++j) {
        int n = n0 + ty + j * 8;
        unsigned short lo = f2bf(tile[2 * tx][ty + j * 8]);
        unsigned short hi = f2bf(tile[2 * tx + 1][ty + j * 8]);
        unsigned int packed = (unsigned int)lo | ((unsigned int)hi << 16);
        *(unsigned int*)(dst + (size_t)n * Kp + k0 + 2 * tx) = packed;
    }
}

// order-pinned LDS fragment read (volatile asm => issue order == source order)
#define DSR(d, ad, off) asm volatile("ds_read_b128 %0, %1 offset:" off : "=v"(d) : "v"(ad))
// counted lgkm gate + scheduling fence (rule #18)
#define GATE(n) do { asm volatile("s_waitcnt lgkmcnt(" #n ")" ::: "memory"); \
                     __builtin_amdgcn_sched_barrier(0); } while (0)

// ======== GEMM1: 256x256, BK=64, 4-phase / 1-barrier-per-phase (R10) ========
// NEW (R12): bm-major XCD map. XCD x owns bm in [4x,4x+4), all 8 (side,bn)
// combos. A (331MB, the big operand) is fetched from HBM ONCE; B (41MB << L3)
// is the replicated operand and L3 absorbs the re-reads. R10's (side,bn)-major
// map replicated A ~4x (FETCH 667MB).
__global__ __launch_bounds__(512, 2)
void gemm1_4p(const unsigned short* __restrict__ Abf,
              const unsigned short* __restrict__ W1t,
              const float* __restrict__ b1u, const float* __restrict__ b1i,
              unsigned short* __restrict__ H1) {
    __shared__ __align__(16) unsigned short lds_[81920];   // A 3x16384, B 2x16384 @49152

    const int t  = threadIdx.x;
    const int lane = t & 63, wv = t >> 6;
    const int wm = wv >> 2, wn = wv & 3;
    const int rA = lane & 15, kg = lane >> 4;

    // bm-major XCD map: raw linear id -> xcd = id&7 -> pos chunk of 32
    const int id   = blockIdx.y * 8 + blockIdx.x;
    const int pos  = (id & 7) * 32 + (id >> 3);
    const int bm   = pos >> 3;
    const int bxc  = pos & 7;
    const int side = bxc >> 2, bn = bxc & 3;

    const unsigned short* AbfS = Abf + (size_t)side * NB * KP;
    const unsigned short* W1tS = W1t + (size_t)side * HID * KP;
    const float* bias = side ? b1i : b1u;
    unsigned short* Cout = H1 + (size_t)side * NB * HID;

    const int rowSA = bm * 256 + (t >> 3);
    const int rowSB = bn * 256 + (t >> 3);
    const int kcl   = ((t & 7) ^ ((t >> 3) & 7)) * 8;

    const int xk0 = ((0 * 4 + kg) ^ (rA & 7)) * 8;
    const int xk1 = ((1 * 4 + kg) ^ (rA & 7)) * 8;

    const unsigned ldsB = (unsigned)(size_t)lds_;
    const unsigned aC0 = ldsB + wm * 16384 + rA * 128 + xk0 * 2;
    const unsigned aC1 = ldsB + wm * 16384 + rA * 128 + xk1 * 2;
    const unsigned bC0 = ldsB + 98304 + (wn >> 1) * 16384 + (wn & 1) * 8192 + rA * 128 + xk0 * 2;
    const unsigned bC1 = ldsB + 98304 + (wn >> 1) * 16384 + (wn & 1) * 8192 + rA * 128 + xk1 * 2;

    f32x4 acc[8][4] = {};
    bf16x8 a[4][2], b[4][2];

    auto stA = [&](int tile, int h, int buf) {
        const unsigned short* s = AbfS + (size_t)(rowSA + h * 128) * KP + tile * 64 + kcl;
        __builtin_amdgcn_global_load_lds((gas_cp)s, (las_p)(lds_ + buf * 16384 + h * 8192 + wv * 512), 16, 0, 0);
        __builtin_amdgcn_global_load_lds((gas_cp)(s + (size_t)64 * KP), (las_p)(lds_ + buf * 16384 + h * 8192 + 4096 + wv * 512), 16, 0, 0);
    };
    auto stB = [&](int tile, int h, int par) {
        const unsigned short* s = W1tS + (size_t)(rowSB + h * 128) * KP + tile * 64 + kcl;
        __builtin_amdgcn_global_load_lds((gas_cp)s, (las_p)(lds_ + 49152 + par * 16384 + h * 8192 + wv * 512), 16, 0, 0);
        __builtin_amdgcn_global_load_lds((gas_cp)(s + (size_t)64 * KP), (las_p)(lds_ + 49152 + par * 16384 + h * 8192 + 4096 + wv * 512), 16, 0, 0);
    };

    auto rdB01 = [&](int par) {
        unsigned b0 = bC0 + par * 32768, b1 = bC1 + par * 32768;
        DSR(b[0][0], b0, "0");    DSR(b[0][1], b1, "0");
        DSR(b[1][0], b0, "2048"); DSR(b[1][1], b1, "2048");
    };
    auto rdB23 = [&](int par) {
        unsigned b0 = bC0 + par * 32768 + 4096, b1 = bC1 + par * 32768 + 4096;
        DSR(b[2][0], b0, "0");    DSR(b[2][1], b1, "0");
        DSR(b[3][0], b0, "2048"); DSR(b[3][1], b1, "2048");
    };
    auto rdA4 = [&](int buf, int mq) {
        unsigned a0 = aC0 + buf * 32768 + mq * 8192, a1 = aC1 + buf * 32768 + mq * 8192;
        DSR(a[0][0], a0, "0");    DSR(a[0][1], a1, "0");
        DSR(a[1][0], a0, "2048"); DSR(a[1][1], a1, "2048");
        DSR(a[2][0], a0, "4096"); DSR(a[2][1], a1, "4096");
        DSR(a[3][0], a0, "6144"); DSR(a[3][1], a1, "6144");
    };
    auto mmj = [&](int mq, int j, int nq) {
        acc[mq*4+j][nq*2+0] = __builtin_amdgcn_mfma_f32_16x16x32_bf16(a[j][0], b[nq*2+0][0], acc[mq*4+j][nq*2+0], 0, 0, 0);
        acc[mq*4+j][nq*2+0] = __builtin_amdgcn_mfma_f32_16x16x32_bf16(a[j][1], b[nq*2+0][1], acc[mq*4+j][nq*2+0], 0, 0, 0);
        acc[mq*4+j][nq*2+1] = __builtin_amdgcn_mfma_f32_16x16x32_bf16(a[j][0], b[nq*2+1][0], acc[mq*4+j][nq*2+1], 0, 0, 0);
        acc[mq*4+j][nq*2+1] = __builtin_amdgcn_mfma_f32_16x16x32_bf16(a[j][1], b[nq*2+1][1], acc[mq*4+j][nq*2+1], 0, 0, 0);
    };
    auto mmcol = [&](int mq, int col) {
#pragma unroll
        for (int j = 0; j < 4; ++j) {
            acc[mq*4+j][col] = __builtin_amdgcn_mfma_f32_16x16x32_bf16(a[j][0], b[col][0], acc[mq*4+j][col], 0, 0, 0);
            acc[mq*4+j][col] = __builtin_amdgcn_mfma_f32_16x16x32_bf16(a[j][1], b[col][1], acc[mq*4+j][col], 0, 0, 0);
        }
    };

    // ---- prologue: A(0)->buf0, B(0)->par0, A(1)->buf1; drain A(0)+B(0) ----
    stA(0, 0, 0); stA(0, 1, 0);
    stB(0, 0, 0); stB(0, 1, 0);
    stA(1, 0, 1); stA(1, 1, 1);
    asm volatile("s_waitcnt vmcnt(4)" ::: "memory");
    __builtin_amdgcn_s_barrier();

    int cA0 = 0, cA1 = 1, nA = 2;
    for (int i = 0; i < NI - 1; ++i) {
        const int T1 = 2 * i + 1, S0 = 2 * i + 2, S1 = 2 * i + 3;
        // ---- alpha: tile-even mq0 (16 reads); stage B(T1)->par1 ----
        rdB01(0); rdA4(cA0, 0); rdB23(0);
        stB(T1, 0, 1); stB(T1, 1, 1);
        __builtin_amdgcn_s_setprio(1);
        GATE(10); mmj(0,0,0); GATE(8); mmj(0,1,0); GATE(6); mmj(0,2,0);
        GATE(4);  mmj(0,3,0); GATE(2); mmcol(0,2); GATE(0); mmcol(0,3);
        __builtin_amdgcn_s_setprio(0);
        __builtin_amdgcn_s_barrier();
        // ---- beta: tile-even mq1 (8 reads); stage A(S0)->nA; gate B(T1) ----
        rdA4(cA0, 1);
        stA(S0, 0, nA); stA(S0, 1, nA);
        __builtin_amdgcn_s_setprio(1);
        GATE(6); mmj(1,0,0); GATE(4); mmj(1,1,0); GATE(2); mmj(1,2,0);
        GATE(0); mmj(1,3,0); mmcol(1,2); mmcol(1,3);
        __builtin_amdgcn_s_setprio(0);
        asm volatile("s_waitcnt vmcnt(4)" ::: "memory");
        __builtin_amdgcn_s_barrier();
        // ---- gamma: tile-odd mq0 (16 reads); stage B(S0)->par0 ----
        rdB01(1); rdA4(cA1, 0); rdB23(1);
        stB(S0, 0, 0); stB(S0, 1, 0);
        __builtin_amdgcn_s_setprio(1);
        GATE(10); mmj(0,0,0); GATE(8); mmj(0,1,0); GATE(6); mmj(0,2,0);
        GATE(4);  mmj(0,3,0); GATE(2); mmcol(0,2); GATE(0); mmcol(0,3);
        __builtin_amdgcn_s_setprio(0);
        __builtin_amdgcn_s_barrier();
        // ---- delta: tile-odd mq1 (8 reads); stage A(S1)->cA0; gate A(S0)+B(S0) ----
        rdA4(cA1, 1);
        stA(S1, 0, cA0); stA(S1, 1, cA0);
        __builtin_amdgcn_s_setprio(1);
        GATE(6); mmj(1,0,0); GATE(4); mmj(1,1,0); GATE(2); mmj(1,2,0);
        GATE(0); mmj(1,3,0); mmcol(1,2); mmcol(1,3);
        __builtin_amdgcn_s_setprio(0);
        asm volatile("s_waitcnt vmcnt(4)" ::: "memory");
        __builtin_amdgcn_s_barrier();
        // rotate A ring: (cA0,cA1,nA) <- (nA,cA0,cA1)
        int tmp = cA1; cA1 = cA0; cA0 = nA; nA = tmp;
    }
    // ---- final iteration: tiles 2*NI-2 (cA0/par0), 2*NI-1 (cA1/par1) ----
    {
        const int TL = 2 * NI - 1;
        // alpha_L
        rdB01(0); rdA4(cA0, 0); rdB23(0);
        stB(TL, 0, 1); stB(TL, 1, 1);
        __builtin_amdgcn_s_setprio(1);
        GATE(10); mmj(0,0,0); GATE(8); mmj(0,1,0); GATE(6); mmj(0,2,0);
        GATE(4);  mmj(0,3,0); GATE(2); mmcol(0,2); GATE(0); mmcol(0,3);
        __builtin_amdgcn_s_setprio(0);
        __builtin_amdgcn_s_barrier();
        // beta_L
        rdA4(cA0, 1);
        __builtin_amdgcn_s_setprio(1);
        GATE(6); mmj(1,0,0); GATE(4); mmj(1,1,0); GATE(2); mmj(1,2,0);
        GATE(0); mmj(1,3,0); mmcol(1,2); mmcol(1,3);
        __builtin_amdgcn_s_setprio(0);
        asm volatile("s_waitcnt vmcnt(0)" ::: "memory");
        __builtin_amdgcn_s_barrier();
        // gamma_L
        rdB01(1); rdA4(cA1, 0); rdB23(1);
        __builtin_amdgcn_s_setprio(1);
        GATE(10); mmj(0,0,0); GATE(8); mmj(0,1,0); GATE(6); mmj(0,2,0);
        GATE(4);  mmj(0,3,0); GATE(2); mmcol(0,2); GATE(0); mmcol(0,3);
        __builtin_amdgcn_s_setprio(0);
        __builtin_amdgcn_s_barrier();
        // delta_L
        rdA4(cA1, 1);
        __builtin_amdgcn_s_setprio(1);
        GATE(6); mmj(1,0,0); GATE(4); mmj(1,1,0); GATE(2); mmj(1,2,0);
        GATE(0); mmj(1,3,0); mmcol(1,2); mmcol(1,3);
        __builtin_amdgcn_s_setprio(0);
    }

    // epilogue: frag row = kg*4+reg, col = rA; bias+relu -> bf16
    const int rowbase = bm * 256 + wm * 128 + kg * 4;
    const int colbase = bn * 256 + wn * 64 + rA;
#pragma unroll
    for (int ni = 0; ni < 4; ++ni) {
        const int col = colbase + ni * 16;
        const float bv = bias[col];
#pragma unroll
        for (int mi = 0; mi < 8; ++mi) {
#pragma unroll
            for (int rr = 0; rr < 4; ++rr) {
                float v = fmaxf(acc[mi][ni][rr] + bv, 0.0f);
                Cout[(size_t)(rowbase + mi * 16 + rr) * HID + col] = f2bf(v);
            }
        }
    }
}

// ======== GEMM2 K-split: PQh[kh*2+side] = H1[side][:,kh*512:+512] @ W2t + b2(kh==0) ========
__global__ __launch_bounds__(256, 2)
void gemm2k(const unsigned short* __restrict__ H1,
            const unsigned short* __restrict__ W2t,
            const float* __restrict__ b2u, const float* __restrict__ b2i,
            float* __restrict__ PQh) {
    __shared__ unsigned short As[3 * 4096];
    __shared__ unsigned short Bs[3 * 4096];

    const int t = threadIdx.x, lane = t & 63, wave = t >> 6;
    const int wr = wave >> 1, wc = wave & 1, rA = lane & 15, kg = lane >> 4;
    const int kh = blockIdx.x, bm = blockIdx.y, side = blockIdx.z;
    const int nk = 512 / 32;

    const unsigned short* A  = H1  + (size_t)side * NB * HID + kh * 512;
    const unsigned short* Bt = W2t + (size_t)side * EMB * HID + kh * 512;
    const float* bias = side ? b2i : b2u;
    float* Cout = PQh + (size_t)(kh * 2 + side) * NB * EMB;

    const int srcc = (t & 3) ^ ((t >> 3) & 3);
    const unsigned short* ga = A  + (size_t)(bm * 128 + (t >> 2)) * HID + (size_t)srcc * 8;
    const unsigned short* gb = Bt + (size_t)(t >> 2) * HID + (size_t)srcc * 8;
    const size_t aP = (size_t)64 * HID;

    f32x4 acc[4][4] = {};
    const int swz  = (rA >> 1) & 3;
    const int aoff = (wr * 64 + rA) * 32 + (kg ^ swz) * 8;
    const int boff = (wc * 64 + rA) * 32 + (kg ^ swz) * 8;
    const int wst  = wave * 512;

    auto stage = [&](int buf) {
        const int bo = buf << 12;
        __builtin_amdgcn_global_load_lds((gas_cp)(ga),      (las_p)(As + bo + wst),        16, 0, 0);
        __builtin_amdgcn_global_load_lds((gas_cp)(ga + aP), (las_p)(As + bo + wst + 2048), 16, 0, 0);
        __builtin_amdgcn_global_load_lds((gas_cp)(gb),      (las_p)(Bs + bo + wst),        16, 0, 0);
        __builtin_amdgcn_global_load_lds((gas_cp)(gb + aP), (las_p)(Bs + bo + wst + 2048), 16, 0, 0);
        ga += 32; gb += 32;
    };
    auto compute = [&](int buf) {
        const int bo = buf << 12;
        bf16x8 af[4], bfr[4];
#pragma unroll
        for (int m = 0; m < 4; ++m) af[m]  = *(const bf16x8*)(As + bo + aoff + m * 512);
#pragma unroll
        for (int n = 0; n < 4; ++n) bfr[n] = *(const bf16x8*)(Bs + bo + boff + n * 512);
#pragma unroll
        for (int m = 0; m < 4; ++m)
#pragma unroll
            for (int n = 0; n < 4; ++n)
                acc[m][n] = __builtin_amdgcn_mfma_f32_16x16x32_bf16(af[m], bfr[n], acc[m][n], 0, 0, 0);
    };

    stage(0); stage(1);
    int cur = 0;
    for (int kt = 0; kt < nk - 2; ++kt) {
        int pfb = cur + 2; if (pfb >= 3) pfb -= 3;
        stage(pfb);
        asm volatile("s_waitcnt vmcnt(8)" ::: "memory");
        __builtin_amdgcn_s_barrier();
        compute(cur);
        __builtin_amdgcn_s_barrier();
        cur = (cur + 1 == 3) ? 0 : cur + 1;
    }
    asm volatile("s_waitcnt vmcnt(4)" ::: "memory");
    __builtin_amdgcn_s_barrier();
    compute(cur);
    cur = (cur + 1 == 3) ? 0 : cur + 1;
    asm volatile("s_waitcnt vmcnt(0)" ::: "memory");
    __builtin_amdgcn_s_barrier();
    compute(cur);

    const int rowbase = bm * 128 + wr * 64 + kg * 4;
    const int colbase = wc * 64 + rA;
#pragma unroll
    for (int n = 0; n < 4; ++n) {
        const int col = colbase + n * 16;
        const float bv = (kh == 0) ? bias[col] : 0.0f;
#pragma unroll
        for (int m = 0; m < 4; ++m) {
#pragma unroll
            for (int r = 0; r < 4; ++r) {
                Cout[(size_t)(rowbase + m * 16 + r) * EMB + col] = acc[m][n][r] + bv;
            }
        }
    }
}

// ---- out[i] = sum_e (P0+P1)[i][e] * (Q0+Q1)[i][e] ----
__global__ void rowdot4(const float* __restrict__ PQh, float* __restrict__ out, int n) {
    int gid = blockIdx.x * blockDim.x + threadIdx.x;
    int w = gid >> 6, lane = gid & 63;
    if (w >= n) return;
    const size_t C = (size_t)NB * EMB;
    const float2 p0 = ((const float2*)(PQh + 0 * C + (size_t)w * EMB))[lane];
    const float2 q0 = ((const float2*)(PQh + 1 * C + (size_t)w * EMB))[lane];
    const float2 p1 = ((const float2*)(PQh + 2 * C + (size_t)w * EMB))[lane];
    const float2 q1 = ((const float2*)(PQh + 3 * C + (size_t)w * EMB))[lane];
    const float px = p0.x + p1.x, py = p0.y + p1.y;
    const float qx = q0.x + q1.x, qy = q0.y + q1.y;
    float s = px * qx + py * qy;
#pragma unroll
    for (int off = 32; off; off >>= 1) s += __shfl_down(s, off);
    if (lane == 0) out[w] = s;
}

extern "C" void kernel_launch(void* const* d_in, const int* in_sizes, int n_in,
                              void* d_out, int out_size, void* d_ws, size_t ws_size,
                              hipStream_t stream) {
    const float* user = (const float*)d_in[0];
    const float* item = (const float*)d_in[1];
    const float* Wu1  = (const float*)d_in[2];
    const float* bu1  = (const float*)d_in[3];
    const float* Wu2  = (const float*)d_in[4];
    const float* bu2  = (const float*)d_in[5];
    const float* Wi1  = (const float*)d_in[6];
    const float* bi1  = (const float*)d_in[7];
    const float* Wi2  = (const float*)d_in[8];
    const float* bi2  = (const float*)d_in[9];
    float* out = (float*)d_out;

    char* ws = (char*)d_ws;
    size_t off = 0;
    auto alloc = [&](size_t bytes) {
        char* p = ws + off;
        off += (bytes + 255) & ~(size_t)255;
        return p;
    };

    unsigned short* W1t = (unsigned short*)alloc((size_t)2 * HID * KP * 2);  // [2][1024][10112]
    unsigned short* W2t = (unsigned short*)alloc((size_t)2 * EMB * HID * 2); // [2][128][1024]
    float* PQh = (float*)alloc((size_t)4 * NB * EMB * 4);                    // [kh*2+side][8192][128]
    unsigned short* H1 = (unsigned short*)alloc((size_t)2 * NB * HID * 2);   // [2][8192][1024]
    unsigned short* Abf = (unsigned short*)alloc((size_t)2 * NB * KP * 2);   // [2][8192][10112]

    dim3 blk(256);
    conv_transpose<<<dim3(KP / 64, HID / 32), blk, 0, stream>>>(Wu1, W1t,                      DIN, HID, KP);
    conv_transpose<<<dim3(KP / 64, HID / 32), blk, 0, stream>>>(Wi1, W1t + (size_t)HID * KP,   DIN, HID, KP);
    conv_transpose<<<dim3(HID / 64, EMB / 32), blk, 0, stream>>>(Wu2, W2t,                     HID, EMB, HID);
    conv_transpose<<<dim3(HID / 64, EMB / 32), blk, 0, stream>>>(Wi2, W2t + (size_t)EMB * HID, HID, EMB, HID);

    conv_pad2<<<dim3((KP / 4 + 255) / 256, NB, 2), blk, 0, stream>>>(user, item, Abf);
    gemm1_4p<<<dim3(8, 32), dim3(512), 0, stream>>>(Abf, W1t, bu1, bi1, H1);
    gemm2k<<<dim3(2, 64, 2), blk, 0, stream>>>(H1, W2t, bu2, bi2, PQh);
    rowdot4<<<(NB * 64) / 256, blk, 0, stream>>>(PQh, out, NB);
}